// Round 2
// baseline (429.866 us; speedup 1.0000x reference)
//
#include <hip/hip_runtime.h>

// VectorQuantizer: x (64,64,64,64) f32, embeddings (64,512) f32
// rows N = 64^3 = 262144, D = 64, K = 512
// out: quantized_st (16777216 f32) ++ loss (1 f32)
//
// Strategy: bit-emulate the numpy fp32 reference:
//   dist = R(R(xnorm + enorm_k) - 2*sim_k)  on the ulp(~64) grid,
//   xnorm via numpy AVX512 pairwise order, sim via sequential FMA chain
//   (OpenBLAS sgemm k-loop), enorm via sequential axis-0 adds,
//   argmin = first index of strict minimum.

#define NROWS 262144
#define DIM 64
#define KCODES 512
#define NELEM 16777216

// Prep: transpose embeddings (ET[k][i] = E[i][k]) and per-code squared norms
// with numpy's rounding: temp = R(e*e), then sequential adds over i (axis-0
// reduce is row-sequential, not pairwise). Also zero the loss accumulator.
__global__ void vq_prep(const float* __restrict__ E, float* __restrict__ ET,
                        float* __restrict__ enorm, float* __restrict__ loss) {
    int k = blockIdx.x * blockDim.x + threadIdx.x;
    if (k == 0) *loss = 0.f;
    if (k >= KCODES) return;
    float s = 0.f;
    for (int i = 0; i < DIM; ++i) {
        float v = E[i * KCODES + k];          // coalesced across lanes
        ET[k * DIM + i] = v;
        s = __fadd_rn(s, __fmul_rn(v, v));    // separate mul/add roundings (no fma!)
    }
    enorm[k] = s;
}

__global__ __launch_bounds__(256, 4)
void vq_main(const float* __restrict__ x, const float* __restrict__ E,
             const float* __restrict__ ET, const float* __restrict__ enorm,
             float* __restrict__ out, float* __restrict__ loss) {
    const int r = blockIdx.x * blockDim.x + threadIdx.x;   // one row per thread
    const float* xr = x + (size_t)r * DIM;

    // Row into registers.
    float z[DIM];
    #pragma unroll
    for (int j = 0; j < DIM / 4; ++j) {
        float4 t = ((const float4*)xr)[j];
        z[4*j+0] = t.x; z[4*j+1] = t.y; z[4*j+2] = t.z; z[4*j+3] = t.w;
    }

    // xnorm = np.sum(z*z) with numpy's AVX512 pairwise order for n=64:
    //   v_j = (s_j + s_{j+16}) + (s_{j+32} + s_{j+48}),  j = 0..15
    //   then halving tree over 16 lanes: +8, +4, then ((c0+c2)+(c1+c3)).
    float v[16];
    #pragma unroll
    for (int j = 0; j < 16; ++j) {
        float a = __fadd_rn(__fmul_rn(z[j],      z[j]),
                            __fmul_rn(z[j + 16], z[j + 16]));
        float b = __fadd_rn(__fmul_rn(z[j + 32], z[j + 32]),
                            __fmul_rn(z[j + 48], z[j + 48]));
        v[j] = __fadd_rn(a, b);
    }
    float u[8];
    #pragma unroll
    for (int j = 0; j < 8; ++j) u[j] = __fadd_rn(v[j], v[j + 8]);
    float c[4];
    #pragma unroll
    for (int j = 0; j < 4; ++j) c[j] = __fadd_rn(u[j], u[j + 4]);
    const float xnorm = __fadd_rn(__fadd_rn(c[0], c[2]), __fadd_rn(c[1], c[3]));

    // argmin over k of dist_k = R(R(xnorm + enorm_k) - 2*sim_k),
    // sim_k = sequential fp32 FMA chain over i (BLAS microkernel order).
    // Strict < with ascending k == numpy argmin first-index tie-break.
    float best = 3.4e38f;
    int idx = 0;

    for (int kt = 0; kt < KCODES; kt += 16) {
        float acc[16];
        #pragma unroll
        for (int j = 0; j < 16; ++j) acc[j] = 0.f;
        #pragma unroll
        for (int i = 0; i < DIM; ++i) {
            const float* Er = E + i * KCODES + kt;  // wave-uniform -> s_load, L2-hot
            float zi = z[i];
            #pragma unroll
            for (int j = 0; j < 16; ++j)
                acc[j] = __fmaf_rn(zi, Er[j], acc[j]);
        }
        #pragma unroll
        for (int j = 0; j < 16; ++j) {
            float t1   = __fadd_rn(xnorm, enorm[kt + j]);
            float dist = __fadd_rn(t1, -2.0f * acc[j]);   // *2 exact, one rounding
            if (dist < best) { best = dist; idx = kt + j; }
        }
    }

    // Gather winning code; emulate quantized_st = R(x + R(q - x)); loss uses
    // d = R(q - x), squared with its own rounding.
    const float4* q4 = (const float4*)(ET + idx * DIM);
    float4* o4 = (float4*)(out + (size_t)r * DIM);
    float sq = 0.f;
    #pragma unroll
    for (int j = 0; j < DIM / 4; ++j) {
        float4 q = q4[j];
        float d0 = __fadd_rn(q.x, -z[4*j+0]);
        float d1 = __fadd_rn(q.y, -z[4*j+1]);
        float d2 = __fadd_rn(q.z, -z[4*j+2]);
        float d3 = __fadd_rn(q.w, -z[4*j+3]);
        float4 o;
        o.x = __fadd_rn(z[4*j+0], d0);
        o.y = __fadd_rn(z[4*j+1], d1);
        o.z = __fadd_rn(z[4*j+2], d2);
        o.w = __fadd_rn(z[4*j+3], d3);
        o4[j] = o;
        sq += d0*d0 + d1*d1 + d2*d2 + d3*d3;
    }

    // loss = 1.25 * mean(d^2): wave shuffle-reduce -> block -> one atomic.
    #pragma unroll
    for (int off = 32; off > 0; off >>= 1)
        sq += __shfl_down(sq, off, 64);
    __shared__ float wsum[4];
    const int lane = threadIdx.x & 63;
    const int wid  = threadIdx.x >> 6;
    if (lane == 0) wsum[wid] = sq;
    __syncthreads();
    if (threadIdx.x == 0) {
        float tot = wsum[0] + wsum[1] + wsum[2] + wsum[3];
        atomicAdd(loss, tot * (1.25f / (float)NELEM));
    }
}

extern "C" void kernel_launch(void* const* d_in, const int* in_sizes, int n_in,
                              void* d_out, int out_size, void* d_ws, size_t ws_size,
                              hipStream_t stream) {
    const float* x = (const float*)d_in[0];        // 16777216
    const float* E = (const float*)d_in[1];        // 64*512
    float* out  = (float*)d_out;                   // quantized_st
    float* loss = out + NELEM;                     // scalar slot
    float* ET    = (float*)d_ws;                   // 512*64 floats
    float* enorm = ET + KCODES * DIM;              // 512 floats

    vq_prep<<<2, 256, 0, stream>>>(E, ET, enorm, loss);
    vq_main<<<NROWS / 256, 256, 0, stream>>>(x, E, ET, enorm, out, loss);
}

// Round 3
// 412.787 us; speedup vs baseline: 1.0414x; 1.0414x over previous
//
#include <hip/hip_runtime.h>

// VectorQuantizer: x (64,64,64,64) f32, embeddings (64,512) f32
// rows N = 64^3 = 262144, D = 64, K = 512
// out: quantized_st (16777216 f32) ++ loss (1 f32)
//
// Bit-emulates the numpy fp32 reference (verified absmax 0.0 in round 2):
//   dist = R(R(xnorm + enorm_k) - 2*sim_k), sim via sequential fp32 FMA
//   chain over i, xnorm via numpy AVX512 pairwise order, enorm via
//   sequential non-fused adds, argmin = first index of strict minimum.
//
// Perf structure (round 3): operand roles swapped vs round 2. Each lane owns
// 4 codes -> E read via coalesced per-lane float4 (L2-hot); x staged in LDS
// per block and broadcast-read (uniform ds_read_b64, conflict-free). Block =
// 4 waves = 32 rows x (2 k-groups of 256). VALU-bound by construction.

#define NROWS 262144
#define DIM 64
#define KCODES 512
#define NELEM 16777216

// Prep: transpose embeddings (ET[k][i] = E[i][k]) and per-code squared norms
// with numpy's rounding: R(e*e) then sequential adds (no fma). Zero loss.
__global__ void vq_prep(const float* __restrict__ E, float* __restrict__ ET,
                        float* __restrict__ enorm, float* __restrict__ loss) {
    int k = blockIdx.x * blockDim.x + threadIdx.x;
    if (k == 0) *loss = 0.f;
    if (k >= KCODES) return;
    float s = 0.f;
    for (int i = 0; i < DIM; ++i) {
        float v = E[i * KCODES + k];
        ET[k * DIM + i] = v;
        s = __fadd_rn(s, __fmul_rn(v, v));
    }
    enorm[k] = s;
}

// xnorm[r] = np.sum(x_r^2) in numpy's AVX512 pairwise order for n=64
// (identical code to the round-2 in-kernel version that bit-matched).
__global__ void vq_xnorm(const float* __restrict__ x, float* __restrict__ xn) {
    int r = blockIdx.x * blockDim.x + threadIdx.x;
    const float4* xr = (const float4*)(x + (size_t)r * DIM);
    float z[DIM];
    #pragma unroll
    for (int j = 0; j < DIM / 4; ++j) {
        float4 t = xr[j];
        z[4*j+0] = t.x; z[4*j+1] = t.y; z[4*j+2] = t.z; z[4*j+3] = t.w;
    }
    float v[16];
    #pragma unroll
    for (int j = 0; j < 16; ++j) {
        float a = __fadd_rn(__fmul_rn(z[j],      z[j]),
                            __fmul_rn(z[j + 16], z[j + 16]));
        float b = __fadd_rn(__fmul_rn(z[j + 32], z[j + 32]),
                            __fmul_rn(z[j + 48], z[j + 48]));
        v[j] = __fadd_rn(a, b);
    }
    float u[8];
    #pragma unroll
    for (int j = 0; j < 8; ++j) u[j] = __fadd_rn(v[j], v[j + 8]);
    float c[4];
    #pragma unroll
    for (int j = 0; j < 4; ++j) c[j] = __fadd_rn(u[j], u[j + 4]);
    xn[r] = __fadd_rn(__fadd_rn(c[0], c[2]), __fadd_rn(c[1], c[3]));
}

__global__ __launch_bounds__(256)
void vq_main(const float* __restrict__ x, const float* __restrict__ E,
             const float* __restrict__ ET, const float* __restrict__ enorm,
             const float* __restrict__ xnorm,
             float* __restrict__ out, float* __restrict__ loss) {
    __shared__ float xt[32 * DIM];          // 8 KB x-tile, row-major
    __shared__ float combD[2][2][16];       // [kg][rg][row]
    __shared__ int   combK[2][2][16];
    __shared__ float lsum[2];

    const int t    = threadIdx.x;
    const int w    = t >> 6;
    const int lane = t & 63;
    const int kg   = w >> 1;                // k-group: 0 or 1 (256 codes each)
    const int rg   = w & 1;                 // row-group: 0 or 1 (16 rows each)
    const int row0 = blockIdx.x * 32;

    // Stage 32 rows of x into LDS (fully coalesced float4).
    {
        const float4* xg = (const float4*)(x + (size_t)row0 * DIM);
        float4* xs = (float4*)xt;
        xs[t]       = xg[t];
        xs[t + 256] = xg[t + 256];
    }
    __syncthreads();

    const int kbase = kg * 256 + lane * 4;  // this lane's 4 contiguous codes
    const float4 en = *(const float4*)(enorm + kbase);

    // sim accumulators: acc[j][r], j = code offset 0..3, r = row 0..15.
    float acc[4][16];
    #pragma unroll
    for (int j = 0; j < 4; ++j)
        #pragma unroll
        for (int r = 0; r < 16; ++r) acc[j][r] = 0.f;

    const float* Er = E + kbase;
    const float* zrow = xt + rg * 16 * DIM;

    // K-loop over i in chunks of 2: E via coalesced float4 (1 KB/wave),
    // z via wave-uniform ds_read_b64 broadcasts. Sequential-i FMA chain
    // preserved exactly (i0 then i0+1).
    for (int c = 0; c < DIM / 2; ++c) {
        const int i0 = c * 2;
        const float4 e0 = *(const float4*)(Er + (size_t)i0 * KCODES);
        const float4 e1 = *(const float4*)(Er + (size_t)(i0 + 1) * KCODES);
        #pragma unroll
        for (int r = 0; r < 16; ++r) {
            const float2 z2 = *(const float2*)(zrow + r * DIM + i0);
            acc[0][r] = __fmaf_rn(z2.x, e0.x, acc[0][r]);
            acc[1][r] = __fmaf_rn(z2.x, e0.y, acc[1][r]);
            acc[2][r] = __fmaf_rn(z2.x, e0.z, acc[2][r]);
            acc[3][r] = __fmaf_rn(z2.x, e0.w, acc[3][r]);
            acc[0][r] = __fmaf_rn(z2.y, e1.x, acc[0][r]);
            acc[1][r] = __fmaf_rn(z2.y, e1.y, acc[1][r]);
            acc[2][r] = __fmaf_rn(z2.y, e1.z, acc[2][r]);
            acc[3][r] = __fmaf_rn(z2.y, e1.w, acc[3][r]);
        }
    }

    // Per row: dist over this lane's 4 codes (ascending k, strict < keeps
    // first index), then 64-lane butterfly with (d, k) tie rule, then
    // cross-wave (k-group) combine via LDS.
    #pragma unroll
    for (int r = 0; r < 16; ++r) {
        const float xn = xnorm[row0 + rg * 16 + r];   // wave-uniform s_load
        float bd; int bk;
        {
            float t1 = __fadd_rn(xn, en.x);
            bd = __fadd_rn(t1, -2.0f * acc[0][r]); bk = kbase;
        }
        {
            float t1 = __fadd_rn(xn, en.y);
            float d = __fadd_rn(t1, -2.0f * acc[1][r]);
            if (d < bd) { bd = d; bk = kbase + 1; }
        }
        {
            float t1 = __fadd_rn(xn, en.z);
            float d = __fadd_rn(t1, -2.0f * acc[2][r]);
            if (d < bd) { bd = d; bk = kbase + 2; }
        }
        {
            float t1 = __fadd_rn(xn, en.w);
            float d = __fadd_rn(t1, -2.0f * acc[3][r]);
            if (d < bd) { bd = d; bk = kbase + 3; }
        }
        #pragma unroll
        for (int off = 32; off > 0; off >>= 1) {
            float od = __shfl_xor(bd, off, 64);
            int   ok = __shfl_xor(bk, off, 64);
            if (od < bd || (od == bd && ok < bk)) { bd = od; bk = ok; }
        }
        if (lane == 0) { combD[kg][rg][r] = bd; combK[kg][rg][r] = bk; }
    }
    __syncthreads();

    // k-group 0 waves finish their 16 rows: combine, gather code, write out,
    // accumulate loss.
    if (kg == 0) {
        float part = 0.f;
        #pragma unroll
        for (int r = 0; r < 16; ++r) {
            const float d0 = combD[0][rg][r], d1 = combD[1][rg][r];
            const int   k0 = combK[0][rg][r], k1 = combK[1][rg][r];
            const int idx = (d1 < d0 || (d1 == d0 && k1 < k0)) ? k1 : k0;
            const int row = row0 + rg * 16 + r;
            const float q = ET[idx * DIM + lane];        // coalesced 256B gather
            const float z = xt[(rg * 16 + r) * DIM + lane];
            const float dd = __fadd_rn(q, -z);
            out[(size_t)row * DIM + lane] = __fadd_rn(z, dd);
            part = __fmaf_rn(dd, dd, part);
        }
        #pragma unroll
        for (int off = 32; off > 0; off >>= 1)
            part += __shfl_down(part, off, 64);
        if (lane == 0) lsum[rg] = part;
    }
    __syncthreads();
    if (t == 0)
        atomicAdd(loss, (lsum[0] + lsum[1]) * (1.25f / (float)NELEM));
}

extern "C" void kernel_launch(void* const* d_in, const int* in_sizes, int n_in,
                              void* d_out, int out_size, void* d_ws, size_t ws_size,
                              hipStream_t stream) {
    const float* x = (const float*)d_in[0];        // 16777216
    const float* E = (const float*)d_in[1];        // 64*512
    float* out  = (float*)d_out;                   // quantized_st
    float* loss = out + NELEM;                     // scalar slot
    float* ET    = (float*)d_ws;                   // 512*64
    float* enorm = ET + KCODES * DIM;              // 512
    float* xn    = enorm + KCODES;                 // 262144

    vq_prep<<<2, 256, 0, stream>>>(E, ET, enorm, loss);
    vq_xnorm<<<NROWS / 256, 256, 0, stream>>>(x, xn);
    vq_main<<<NROWS / 32, 256, 0, stream>>>(x, E, ET, enorm, xn, out, loss);
}

// Round 4
// 323.080 us; speedup vs baseline: 1.3305x; 1.2777x over previous
//
#include <hip/hip_runtime.h>

// VectorQuantizer: x (64,64,64,64) f32, embeddings (64,512) f32
// rows N = 64^3 = 262144, D = 64, K = 512
// out: quantized_st (16777216 f32) ++ loss (1 f32)
//
// Structure (round 4): bf16-split MFMA computes approximate distances
// (error ~<=1e-4); per-row top-2 keys detect near-ties; a fixup kernel
// re-resolves flagged rows (~2-3k) with the bit-exact numpy emulation
// (dist = R(R(xnorm+enorm_k)-2*sim_k), sequential FMA chain, AVX512
// pairwise xnorm, first-index argmin) verified absmax 0.0 in rounds 2/3.

typedef __attribute__((ext_vector_type(8))) __bf16 bf16x8;
typedef __attribute__((ext_vector_type(16))) float f32x16;

#define NROWS   262144
#define DIM     64
#define KCODES  512
#define NELEM   16777216
#define LISTCAP 16384

// ws layout (float offsets)
#define WS_ET     0        // 512*64 code-major embeddings
#define WS_EN     32768    // exact enorm (numpy rounding)
#define WS_EN8    33280    // enorm + 8 (approx domain)
#define WS_PACKH  33792    // uint4[4096]: e_hi B-fragments
#define WS_PACKL  50176    // uint4[4096]: e_lo B-fragments
#define WS_CNT    66560    // flag counter (int)
#define WS_LIST   66576    // flagged rows: (row<<9)|idx

__device__ __forceinline__ unsigned short f2bf(float f) {  // RNE float->bf16 bits
    unsigned int u = __float_as_uint(f);
    return (unsigned short)((u + 0x7FFFu + ((u >> 16) & 1u)) >> 16);
}
__device__ __forceinline__ float bf2f(unsigned short b) {
    return __uint_as_float(((unsigned int)b) << 16);
}

union FragU { uint4 q; bf16x8 v; unsigned short u[8]; };

// ---- prep: ET transpose, exact enorm (R(e*e) + sequential adds), enorm+8,
// zero loss + flag counter.
__global__ void vq_prep(const float* __restrict__ E, float* __restrict__ ET,
                        float* __restrict__ en, float* __restrict__ en8,
                        float* __restrict__ loss, int* __restrict__ cnt) {
    int k = blockIdx.x * blockDim.x + threadIdx.x;   // 0..511
    if (k == 0) *loss = 0.f;
    if (k == 1) *cnt = 0;
    float s = 0.f;
    for (int i = 0; i < DIM; ++i) {
        float v = E[i * KCODES + k];
        ET[k * DIM + i] = v;
        s = __fadd_rn(s, __fmul_rn(v, v));
    }
    en[k] = s;
    en8[k] = __fadd_rn(s, 8.0f);
}

// ---- pack e_hi / e_lo into 32x32x16 B-fragment order:
// frag id = (t*4+c)*64+lane holds B[k = c*16+(lane>>5)*8+j][n = t*32+(lane&31)]
__global__ void vq_pack(const float* __restrict__ E, uint4* __restrict__ packH,
                        uint4* __restrict__ packL) {
    const int id = blockIdx.x * 256 + threadIdx.x;   // 0..4095
    const int lane = id & 63;
    const int c = (id >> 6) & 3;
    const int t = id >> 8;
    const int n = t * 32 + (lane & 31);
    const int kb = c * 16 + (lane >> 5) * 8;
    FragU H, L;
    #pragma unroll
    for (int j = 0; j < 8; ++j) {
        float vv = E[(size_t)(kb + j) * KCODES + n];
        unsigned short hb = f2bf(vv);
        H.u[j] = hb;
        L.u[j] = f2bf(vv - bf2f(hb));
    }
    packH[id] = H.q;
    packL[id] = L.q;
}

// ---- main: 8 waves x 64 rows = 512 rows/block, grid 512.
// Each wave: two 32x32 M-tiles over 16 col-tiles; 24 MFMA per tile-pair.
__global__ __launch_bounds__(512, 2)
void vq_main(const float* __restrict__ x, const float* __restrict__ ET,
             const float* __restrict__ en8, const uint4* __restrict__ packH,
             const uint4* __restrict__ packL, float* __restrict__ outp,
             float* __restrict__ loss, int* __restrict__ cnt,
             int* __restrict__ list) {
    __shared__ uint4 eh[4096];                       // 64 KB: e_hi fragments
    const int tid = threadIdx.x;
    for (int i = tid; i < 4096; i += 512) eh[i] = packH[i];

    const int wv   = tid >> 6;
    const int lane = tid & 63;
    const int h    = lane >> 5;
    const int l31  = lane & 31;
    const size_t rowbase = (size_t)blockIdx.x * 512 + (size_t)wv * 64;

    // A fragments: z_hi/z_lo bf16 split, A[m=lane&31][k=c*16+h*8+j]
    FragU ah[2][4], al[2][4];
    #pragma unroll
    for (int m = 0; m < 2; ++m) {
        const float* xr = x + (rowbase + m * 32 + l31) * DIM;
        #pragma unroll
        for (int c = 0; c < 4; ++c) {
            const float* xp = xr + c * 16 + h * 8;
            float4 p0 = *(const float4*)xp;
            float4 p1 = *(const float4*)(xp + 4);
            float vv[8] = {p0.x, p0.y, p0.z, p0.w, p1.x, p1.y, p1.z, p1.w};
            #pragma unroll
            for (int j = 0; j < 8; ++j) {
                unsigned short hb = f2bf(vv[j]);
                ah[m][c].u[j] = hb;
                al[m][c].u[j] = f2bf(vv[j] - bf2f(hb));
            }
        }
    }

    float en8v[16];
    #pragma unroll
    for (int t = 0; t < 16; ++t) en8v[t] = en8[t * 32 + l31];

    unsigned int b1[2][16], b2[2][16];               // per-row-slot top-2 keys
    #pragma unroll
    for (int m = 0; m < 2; ++m)
        #pragma unroll
        for (int r = 0; r < 16; ++r) { b1[m][r] = 0xFFFFFFFFu; b2[m][r] = 0xFFFFFFFFu; }

    __syncthreads();

    for (int t = 0; t < 16; ++t) {
        FragU bh[4], bl[4];
        #pragma unroll
        for (int c = 0; c < 4; ++c) {
            bh[c].q = eh[(t * 4 + c) * 64 + lane];
            bl[c].q = packL[(t * 4 + c) * 64 + lane];   // L2-hot (64 KB)
        }
        f32x16 A0, A1;
        #pragma unroll
        for (int r = 0; r < 16; ++r) { A0[r] = 0.f; A1[r] = 0.f; }
        #pragma unroll
        for (int c = 0; c < 4; ++c) {                    // z_hi * e_hi
            A0 = __builtin_amdgcn_mfma_f32_32x32x16_bf16(ah[0][c].v, bh[c].v, A0, 0, 0, 0);
            A1 = __builtin_amdgcn_mfma_f32_32x32x16_bf16(ah[1][c].v, bh[c].v, A1, 0, 0, 0);
        }
        #pragma unroll
        for (int c = 0; c < 4; ++c) {                    // z_hi * e_lo
            A0 = __builtin_amdgcn_mfma_f32_32x32x16_bf16(ah[0][c].v, bl[c].v, A0, 0, 0, 0);
            A1 = __builtin_amdgcn_mfma_f32_32x32x16_bf16(ah[1][c].v, bl[c].v, A1, 0, 0, 0);
        }
        #pragma unroll
        for (int c = 0; c < 4; ++c) {                    // z_lo * e_hi
            A0 = __builtin_amdgcn_mfma_f32_32x32x16_bf16(al[0][c].v, bh[c].v, A0, 0, 0, 0);
            A1 = __builtin_amdgcn_mfma_f32_32x32x16_bf16(al[1][c].v, bh[c].v, A1, 0, 0, 0);
        }
        // keys: d = enorm+8 - 2*sim > 0; (bits & ~511) | col sorts by dist
        const unsigned int colv = (unsigned int)(t * 32 + l31);
        #pragma unroll
        for (int r = 0; r < 16; ++r) {
            {
                float d = fmaf(-2.f, A0[r], en8v[t]);
                unsigned int key = (__float_as_uint(d) & 0xFFFFFE00u) | colv;
                unsigned int n1 = min(key, b1[0][r]);
                unsigned int mx = max(key, b1[0][r]);
                b2[0][r] = min(b2[0][r], mx);
                b1[0][r] = n1;
            }
            {
                float d = fmaf(-2.f, A1[r], en8v[t]);
                unsigned int key = (__float_as_uint(d) & 0xFFFFFE00u) | colv;
                unsigned int n1 = min(key, b1[1][r]);
                unsigned int mx = max(key, b1[1][r]);
                b2[1][r] = min(b2[1][r], mx);
                b1[1][r] = n1;
            }
        }
    }

    // merge top-2 across the 32-lane half-group; C row = (r&3)+8*(r>>2)+4*h
    float lsq = 0.f;
    #pragma unroll
    for (int m = 0; m < 2; ++m) {
        #pragma unroll
        for (int r = 0; r < 16; ++r) {
            unsigned int B1 = b1[m][r], B2 = b2[m][r];
            #pragma unroll
            for (int off = 1; off <= 16; off <<= 1) {
                unsigned int o1 = (unsigned int)__shfl_xor((int)B1, off, 64);
                unsigned int o2 = (unsigned int)__shfl_xor((int)B2, off, 64);
                unsigned int n1 = min(B1, o1);
                unsigned int mx = max(B1, o1);
                B2 = min(min(B2, o2), mx);
                B1 = n1;
            }
            const int idx = (int)(B1 & 511u);
            const int rowl = (r & 3) + 8 * (r >> 2) + 4 * h;
            const size_t row = rowbase + m * 32 + rowl;
            if (l31 == 0 &&
                ((B2 & 0xFFFFFE00u) - (B1 & 0xFFFFFE00u)) <= (4u << 9)) {
                int slot = atomicAdd(cnt, 1);
                if (slot < LISTCAP)
                    list[slot] = (int)(((unsigned int)row << 9) | (unsigned int)idx);
            }
            // out = R(x + R(q - x)); 32 lanes x 2 cols cover the row
            const float2 q2 = ((const float2*)(ET + idx * DIM))[l31];
            const float2 x2 = ((const float2*)(x + row * DIM))[l31];
            float d0 = __fadd_rn(q2.x, -x2.x);
            float d1 = __fadd_rn(q2.y, -x2.y);
            float2 o;
            o.x = __fadd_rn(x2.x, d0);
            o.y = __fadd_rn(x2.y, d1);
            ((float2*)(outp + row * DIM))[l31] = o;
            lsq = fmaf(d0, d0, lsq);
            lsq = fmaf(d1, d1, lsq);
        }
    }
    #pragma unroll
    for (int off = 32; off > 0; off >>= 1) lsq += __shfl_xor(lsq, off, 64);
    if (lane == 0) atomicAdd(loss, lsq * (1.25f / (float)NELEM));
}

// ---- fixup: one wave per flagged row; full bit-exact numpy emulation over
// all 512 codes (8 codes/lane, sequential-i FMA chains), rewrite if changed.
__global__ void vq_fixup(const float* __restrict__ x, const float* __restrict__ E,
                         const float* __restrict__ ET, const float* __restrict__ en,
                         float* __restrict__ outp, float* __restrict__ loss,
                         const int* __restrict__ cnt, const int* __restrict__ list) {
    const int lane = threadIdx.x & 63;
    const int waveId = (blockIdx.x * blockDim.x + threadIdx.x) >> 6;  // 0..1023
    int total = *cnt;
    if (total > LISTCAP) total = LISTCAP;
    for (int it = waveId; it < total; it += 1024) {
        int e = __builtin_amdgcn_readfirstlane(list[it]);
        const int row = e >> 9;
        const int old = e & 511;
        const float* xr = x + (size_t)row * DIM;
        float z[DIM];
        #pragma unroll
        for (int i = 0; i < 16; ++i) {
            float4 t4 = ((const float4*)xr)[i];
            z[4*i] = t4.x; z[4*i+1] = t4.y; z[4*i+2] = t4.z; z[4*i+3] = t4.w;
        }
        // exact xnorm (numpy AVX512 pairwise)
        float v[16];
        #pragma unroll
        for (int j = 0; j < 16; ++j) {
            float a = __fadd_rn(__fmul_rn(z[j], z[j]), __fmul_rn(z[j+16], z[j+16]));
            float b = __fadd_rn(__fmul_rn(z[j+32], z[j+32]), __fmul_rn(z[j+48], z[j+48]));
            v[j] = __fadd_rn(a, b);
        }
        float u[8];
        #pragma unroll
        for (int j = 0; j < 8; ++j) u[j] = __fadd_rn(v[j], v[j+8]);
        float c4[4];
        #pragma unroll
        for (int j = 0; j < 4; ++j) c4[j] = __fadd_rn(u[j], u[j+4]);
        const float xn = __fadd_rn(__fadd_rn(c4[0], c4[2]), __fadd_rn(c4[1], c4[3]));

        // exact sims: this lane's 8 contiguous codes, sequential-i chains
        float acc[8];
        #pragma unroll
        for (int j = 0; j < 8; ++j) acc[j] = 0.f;
        const float* Ep = E + lane * 8;
        for (int i = 0; i < DIM; ++i) {
            const float4 e0 = ((const float4*)(Ep + (size_t)i * KCODES))[0];
            const float4 e1 = ((const float4*)(Ep + (size_t)i * KCODES))[1];
            const float zi = z[i];
            acc[0] = __fmaf_rn(zi, e0.x, acc[0]);
            acc[1] = __fmaf_rn(zi, e0.y, acc[1]);
            acc[2] = __fmaf_rn(zi, e0.z, acc[2]);
            acc[3] = __fmaf_rn(zi, e0.w, acc[3]);
            acc[4] = __fmaf_rn(zi, e1.x, acc[4]);
            acc[5] = __fmaf_rn(zi, e1.y, acc[5]);
            acc[6] = __fmaf_rn(zi, e1.z, acc[6]);
            acc[7] = __fmaf_rn(zi, e1.w, acc[7]);
        }
        float bd = 3.4e38f; int bk = 0;
        #pragma unroll
        for (int j = 0; j < 8; ++j) {
            int k = lane * 8 + j;
            float t1 = __fadd_rn(xn, en[k]);
            float d = __fadd_rn(t1, -2.0f * acc[j]);
            if (d < bd) { bd = d; bk = k; }
        }
        #pragma unroll
        for (int off = 1; off <= 32; off <<= 1) {
            float od = __shfl_xor(bd, off, 64);
            int   ok = __shfl_xor(bk, off, 64);
            if (od < bd || (od == bd && ok < bk)) { bd = od; bk = ok; }
        }
        if (bk != old) {
            const float xl = xr[lane];
            const float qn = ET[bk * DIM + lane];
            const float qo = ET[old * DIM + lane];
            const float dn = __fadd_rn(qn, -xl);
            const float dd = __fadd_rn(qo, -xl);
            outp[(size_t)row * DIM + lane] = __fadd_rn(xl, dn);
            float dl = __fsub_rn(__fmul_rn(dn, dn), __fmul_rn(dd, dd));
            #pragma unroll
            for (int off = 32; off > 0; off >>= 1) dl += __shfl_xor(dl, off, 64);
            if (lane == 0) atomicAdd(loss, dl * (1.25f / (float)NELEM));
        }
    }
}

extern "C" void kernel_launch(void* const* d_in, const int* in_sizes, int n_in,
                              void* d_out, int out_size, void* d_ws, size_t ws_size,
                              hipStream_t stream) {
    const float* x = (const float*)d_in[0];
    const float* E = (const float*)d_in[1];
    float* out  = (float*)d_out;
    float* loss = out + NELEM;
    float* ws = (float*)d_ws;
    float* ET    = ws + WS_ET;
    float* en    = ws + WS_EN;
    float* en8   = ws + WS_EN8;
    uint4* packH = (uint4*)(ws + WS_PACKH);
    uint4* packL = (uint4*)(ws + WS_PACKL);
    int* cnt  = (int*)(ws + WS_CNT);
    int* list = (int*)(ws + WS_LIST);

    vq_prep<<<2, 256, 0, stream>>>(E, ET, en, en8, loss, cnt);
    vq_pack<<<16, 256, 0, stream>>>(E, packH, packL);
    vq_main<<<512, 512, 0, stream>>>(x, ET, en8, packH, packL, out, loss, cnt, list);
    vq_fixup<<<256, 256, 0, stream>>>(x, E, ET, en, out, loss, cnt, list);
}